// Round 3
// baseline (282.951 us; speedup 1.0000x reference)
//
#include <hip/hip_runtime.h>
#include <hip/hip_bf16.h>
#include <stdint.h>
#include <stddef.h>

#define DEVI __device__ __forceinline__

typedef __attribute__((ext_vector_type(8)))  short bf16x8;
typedef __attribute__((ext_vector_type(4)))  float f32x4;
typedef __attribute__((ext_vector_type(16))) float f32x16;
typedef __attribute__((ext_vector_type(2)))  unsigned u32x2;

DEVI unsigned short f2bf(float f) {
    __hip_bfloat16 h = __float2bfloat16(f);   // RNE
    union { __hip_bfloat16 h; unsigned short u; } v; v.h = h; return v.u;
}
DEVI unsigned pk2(float lo, float hi) {
    return (unsigned)f2bf(lo) | ((unsigned)f2bf(hi) << 16);
}
DEVI f32x4 zero4() { f32x4 z; z[0] = z[1] = z[2] = z[3] = 0.f; return z; }
DEVI f32x16 zero16() {
    f32x16 z;
#pragma unroll
    for (int i = 0; i < 16; ++i) z[i] = 0.f;
    return z;
}

// ---------------------------------------------------------------------------
// ws layout (same as round 1):
//   qbf [1024][64][256] bf16 @ 0           natural
//   kbf [2048][64][256] bf16 @ 33554432    natural
//   vt8 [bh=64][t>>3][col 4096][t&7] bf16 @ 100663296
//   partial [4][4096][128] f32 @ 167772160
//   pbf [4096][128] bf16 @ 176160768
// ---------------------------------------------------------------------------

// ============================ unified proj ============================
// blocks 0..1023: q-image; blocks 1024..3071: kv-image (k+v), XCD t-octet remap.
// Per image: stage X bf16 in LDS [c][p] (stride 260), MFMA with A=X^T-frag,
// B=W^T-frag => D[p][o]: lane holds 4 consecutive p at fixed o -> dwordx2 stores.
__global__ __launch_bounds__(256) void proj_kernel(
    const float* __restrict__ qq, const float* __restrict__ kvg,
    const float* __restrict__ Wq, const float* __restrict__ bq,
    const float* __restrict__ Wk, const float* __restrict__ bk,
    const float* __restrict__ Wv, const float* __restrict__ bv,
    unsigned short* __restrict__ qbf, unsigned short* __restrict__ kbf,
    unsigned short* __restrict__ vt8)
{
    __shared__ unsigned short Xs[64 * 260];   // [c][p], row stride 260 elems (520 B)
    const int tid = threadIdx.x;
    const int w = tid >> 6, lane = tid & 63;
    const int l15 = lane & 15, lg = lane >> 4;
    const int bid = blockIdx.x;
    const bool dual = (bid >= 1024);

    const float *xg, *W1, *B1, *W2, *B2;
    unsigned short* o1;
    int b = 0, t = 0;
    if (dual) {
        const int kvbid = bid - 1024;
        const int L = ((kvbid & 7) << 8) | (kvbid >> 3);  // t-octets share an XCD
        b = L >> 7; t = L & 127;
        xg = kvg + (size_t)L * 16384;
        W1 = Wk; B1 = bk; W2 = Wv; B2 = bv;
        o1 = kbf + (size_t)L * 16384;
    } else {
        xg = qq + (size_t)bid * 16384;
        W1 = Wq; B1 = bq; W2 = Wq; B2 = bq;   // unused, kept valid
        o1 = qbf + (size_t)bid * 16384;
    }

    // ---- stage X -> LDS bf16 (coalesced float4 loads, b64 conflict-free writes)
#pragma unroll
    for (int it = 0; it < 16; ++it) {
        const float* src = xg + it * 1024 + tid * 4;   // c = it*4+w, p = 4*lane
        f32x4 xv = *(const f32x4*)src;
        u32x2 dd;
        dd[0] = pk2(xv[0], xv[1]);
        dd[1] = pk2(xv[2], xv[3]);
        *(u32x2*)(&Xs[(it * 4 + w) * 260 + lane * 4]) = dd;
    }

    // ---- W fragments (B-operand: col=o=l15, k=c contiguous) + biases
    bf16x8 bf1[4][2], bf2[4][2];
    float bias1[4], bias2[4];
#pragma unroll
    for (int ot = 0; ot < 4; ++ot) {
        const int o = ot * 16 + l15;
        bias1[ot] = B1[o];
#pragma unroll
        for (int ks = 0; ks < 2; ++ks) {
            const float* wp = W1 + o * 64 + ks * 32 + lg * 8;
            f32x4 w0 = *(const f32x4*)wp, w1 = *(const f32x4*)(wp + 4);
            bf16x8 a;
#pragma unroll
            for (int j = 0; j < 4; ++j) { a[j] = (short)f2bf(w0[j]); a[4 + j] = (short)f2bf(w1[j]); }
            bf1[ot][ks] = a;
        }
        if (dual) {
            bias2[ot] = B2[o];
#pragma unroll
            for (int ks = 0; ks < 2; ++ks) {
                const float* wp = W2 + o * 64 + ks * 32 + lg * 8;
                f32x4 w0 = *(const f32x4*)wp, w1 = *(const f32x4*)(wp + 4);
                bf16x8 a;
#pragma unroll
                for (int j = 0; j < 4; ++j) { a[j] = (short)f2bf(w0[j]); a[4 + j] = (short)f2bf(w1[j]); }
                bf2[ot][ks] = a;
            }
        }
    }
    __syncthreads();

    // ---- main: per 16-pixel tile, A-frags from LDS, 16x16x32 MFMA, packed stores
#pragma unroll
    for (int pt = 0; pt < 4; ++pt) {
        const int p0 = w * 64 + pt * 16;
        bf16x8 afr[2];
#pragma unroll
        for (int ks = 0; ks < 2; ++ks) {
            bf16x8 e;
#pragma unroll
            for (int j = 0; j < 8; ++j)
                e[j] = (short)Xs[(ks * 32 + lg * 8 + j) * 260 + p0 + l15];
            afr[ks] = e;
        }
        const int pb = p0 + lg * 4;
#pragma unroll
        for (int ot = 0; ot < 4; ++ot) {
            const int o = ot * 16 + l15;
            f32x4 a1 = zero4();
            a1 = __builtin_amdgcn_mfma_f32_16x16x32_bf16(afr[0], bf1[ot][0], a1, 0, 0, 0);
            a1 = __builtin_amdgcn_mfma_f32_16x16x32_bf16(afr[1], bf1[ot][1], a1, 0, 0, 0);
            u32x2 sv;
            sv[0] = pk2(a1[0] + bias1[ot], a1[1] + bias1[ot]);
            sv[1] = pk2(a1[2] + bias1[ot], a1[3] + bias1[ot]);
            *(u32x2*)(o1 + (size_t)o * 256 + pb) = sv;
            if (dual) {
                f32x4 a2 = zero4();
                a2 = __builtin_amdgcn_mfma_f32_16x16x32_bf16(afr[0], bf2[ot][0], a2, 0, 0, 0);
                a2 = __builtin_amdgcn_mfma_f32_16x16x32_bf16(afr[1], bf2[ot][1], a2, 0, 0, 0);
                const int bh = b * 4 + ot;               // o>>4 == ot
                const int colb = l15 * 256 + pb;         // (o&15)*256 + p
                unsigned short* vp = vt8 + (((size_t)bh * 16 + (t >> 3)) * 4096 + colb) * 8 + (t & 7);
                vp[0]  = f2bf(a2[0] + bias2[ot]);
                vp[8]  = f2bf(a2[1] + bias2[ot]);
                vp[16] = f2bf(a2[2] + bias2[ot]);
                vp[24] = f2bf(a2[3] + bias2[ot]);
            }
        }
    }
}

// ============================ sim (Q.K^T partials, K-split x4) ============================
// (round-1 version, verbatim)
__global__ __launch_bounds__(128) void sim_kernel(
    const unsigned short* __restrict__ qbf, const unsigned short* __restrict__ kbf,
    float* __restrict__ partial)
{
    const int tid = threadIdx.x;
    const int w = tid >> 6, lane = tid & 63;
    const int l31 = lane & 31, lh = lane >> 5;
    const int bh = blockIdx.x & 63, ks = blockIdx.x >> 6;
    const int b = bh >> 2, head = bh & 3;
    const int t0 = w * 64;

    const unsigned short* qbase = qbf + (size_t)b * 64 * 16384 + head * 4096;
    const unsigned short* kbase = kbf + (size_t)b * 128 * 16384 + head * 4096;

    f32x16 acc00 = zero16(), acc01 = zero16(), acc10 = zero16(), acc11 = zero16();
    const int kk0 = ks * 1024;
    for (int kk = 0; kk < 64; ++kk) {
        int k = kk0 + kk * 16 + lh * 8;
        bf16x8 a0 = *(const bf16x8*)(qbase + (size_t)(l31)      * 16384 + k);
        bf16x8 a1 = *(const bf16x8*)(qbase + (size_t)(l31 + 32) * 16384 + k);
        bf16x8 b0 = *(const bf16x8*)(kbase + (size_t)(t0 + l31)      * 16384 + k);
        bf16x8 b1 = *(const bf16x8*)(kbase + (size_t)(t0 + 32 + l31) * 16384 + k);
        acc00 = __builtin_amdgcn_mfma_f32_32x32x16_bf16(a0, b0, acc00, 0, 0, 0);
        acc01 = __builtin_amdgcn_mfma_f32_32x32x16_bf16(a0, b1, acc01, 0, 0, 0);
        acc10 = __builtin_amdgcn_mfma_f32_32x32x16_bf16(a1, b0, acc10, 0, 0, 0);
        acc11 = __builtin_amdgcn_mfma_f32_32x32x16_bf16(a1, b1, acc11, 0, 0, 0);
    }

    float* pb = partial + ((size_t)ks * 4096 + (size_t)bh * 64) * 128;
#pragma unroll
    for (int r = 0; r < 16; ++r) {
        int kqr = (r & 3) + 8 * (r >> 2) + 4 * lh;
        pb[(kqr)      * 128 + t0 + l31]      = acc00[r];
        pb[(kqr)      * 128 + t0 + 32 + l31] = acc01[r];
        pb[(kqr + 32) * 128 + t0 + l31]      = acc10[r];
        pb[(kqr + 32) * 128 + t0 + 32 + l31] = acc11[r];
    }
}

// ============================ softmax ============================
__global__ __launch_bounds__(256) void softmax_kernel(
    const float* __restrict__ partial, float* __restrict__ sim_out,
    unsigned short* __restrict__ pbf)
{
    const int tid = threadIdx.x;
    const int w = tid >> 6, lane = tid & 63;
    const int row = blockIdx.x * 4 + w;

    float x0 = 0.f, x1 = 0.f;
#pragma unroll
    for (int s = 0; s < 4; ++s) {
        x0 += partial[((size_t)s * 4096 + row) * 128 + lane];
        x1 += partial[((size_t)s * 4096 + row) * 128 + 64 + lane];
    }
    const float scale = 1.0f / 64.0f;
    x0 *= scale; x1 *= scale;
    float m = fmaxf(x0, x1);
#pragma unroll
    for (int off = 32; off; off >>= 1) m = fmaxf(m, __shfl_xor(m, off));
    float e0 = __expf(x0 - m), e1 = __expf(x1 - m);
    float s = e0 + e1;
#pragma unroll
    for (int off = 32; off; off >>= 1) s += __shfl_xor(s, off);
    float inv = 1.0f / s;
    float p0 = e0 * inv, p1 = e1 * inv;
    sim_out[(size_t)row * 128 + lane]      = p0;
    sim_out[(size_t)row * 128 + 64 + lane] = p1;
    pbf[(size_t)row * 128 + lane]      = f2bf(p0);
    pbf[(size_t)row * 128 + 64 + lane] = f2bf(p1);
}

// ============================ PV ============================
// (round-1 version, verbatim: vt8 layout, coalesced 16B loads)
__global__ __launch_bounds__(256) void pv_kernel(
    const unsigned short* __restrict__ pbf, const unsigned short* __restrict__ vt8,
    float* __restrict__ outp)
{
    const int tid = threadIdx.x;
    const int w = tid >> 6, lane = tid & 63;
    const int l31 = lane & 31, lh = lane >> 5;
    const int bh = blockIdx.x >> 4, cb = blockIdx.x & 15;
    const int b = bh >> 2, head = bh & 3;
    const int col0 = cb * 256 + w * 64;

    const unsigned short* pb = pbf + (size_t)bh * 64 * 128;
    const unsigned short* vb = vt8 + (size_t)bh * 16 * 4096 * 8;

    f32x16 acc00 = zero16(), acc01 = zero16(), acc10 = zero16(), acc11 = zero16();
    for (int kk = 0; kk < 8; ++kk) {
        const int t0 = kk * 16;
        bf16x8 a0 = *(const bf16x8*)(pb + (size_t)(l31)      * 128 + t0 + lh * 8);
        bf16x8 a1 = *(const bf16x8*)(pb + (size_t)(l31 + 32) * 128 + t0 + lh * 8);
        bf16x8 b0 = *(const bf16x8*)(vb + ((size_t)(t0 / 8 + lh) * 4096 + col0 + l31) * 8);
        bf16x8 b1 = *(const bf16x8*)(vb + ((size_t)(t0 / 8 + lh) * 4096 + col0 + 32 + l31) * 8);
        acc00 = __builtin_amdgcn_mfma_f32_32x32x16_bf16(a0, b0, acc00, 0, 0, 0);
        acc01 = __builtin_amdgcn_mfma_f32_32x32x16_bf16(a0, b1, acc01, 0, 0, 0);
        acc10 = __builtin_amdgcn_mfma_f32_32x32x16_bf16(a1, b0, acc10, 0, 0, 0);
        acc11 = __builtin_amdgcn_mfma_f32_32x32x16_bf16(a1, b1, acc11, 0, 0, 0);
    }

    float* ob = outp + (size_t)b * 64 * 16384 + head * 4096;
#pragma unroll
    for (int r = 0; r < 16; ++r) {
        int kqr = (r & 3) + 8 * (r >> 2) + 4 * lh;
        ob[(size_t)(kqr)      * 16384 + col0 + l31]      = acc00[r];
        ob[(size_t)(kqr)      * 16384 + col0 + 32 + l31] = acc01[r];
        ob[(size_t)(kqr + 32) * 16384 + col0 + l31]      = acc10[r];
        ob[(size_t)(kqr + 32) * 16384 + col0 + 32 + l31] = acc11[r];
    }
}

// ============================ launch ============================
extern "C" void kernel_launch(void* const* d_in, const int* in_sizes, int n_in,
                              void* d_out, int out_size, void* d_ws, size_t ws_size,
                              hipStream_t stream)
{
    const float* qq = (const float*)d_in[0];
    const float* kv = (const float*)d_in[1];
    const float* Wq = (const float*)d_in[2];
    const float* bq = (const float*)d_in[3];
    const float* Wk = (const float*)d_in[4];
    const float* bk = (const float*)d_in[5];
    const float* Wv = (const float*)d_in[6];
    const float* bv = (const float*)d_in[7];

    float* outp    = (float*)d_out;
    float* sim_out = outp + (size_t)16777216;

    char* ws = (char*)d_ws;
    unsigned short* qbf     = (unsigned short*)(ws);
    unsigned short* kbf     = (unsigned short*)(ws + 33554432);
    unsigned short* vt8     = (unsigned short*)(ws + 100663296);
    float*          partial = (float*)         (ws + 167772160);
    unsigned short* pbf     = (unsigned short*)(ws + 176160768);
    (void)in_sizes; (void)n_in; (void)out_size; (void)ws_size;

    proj_kernel   <<<dim3(3072), dim3(256), 0, stream>>>(qq, kv, Wq, bq, Wk, bk, Wv, bv,
                                                         qbf, kbf, vt8);
    sim_kernel    <<<dim3(256),  dim3(128), 0, stream>>>(qbf, kbf, partial);
    softmax_kernel<<<dim3(1024), dim3(256), 0, stream>>>(partial, sim_out, pbf);
    pv_kernel     <<<dim3(1024), dim3(256), 0, stream>>>(pbf, vt8, outp);
}

// Round 4
// 193.665 us; speedup vs baseline: 1.4610x; 1.4610x over previous
//
#include <hip/hip_runtime.h>
#include <hip/hip_bf16.h>
#include <stdint.h>
#include <stddef.h>

#define DEVI __device__ __forceinline__

typedef __attribute__((ext_vector_type(8)))  short bf16x8;
typedef __attribute__((ext_vector_type(4)))  float f32x4;
typedef __attribute__((ext_vector_type(16))) float f32x16;
typedef __attribute__((ext_vector_type(2)))  unsigned u32x2;

DEVI unsigned short f2bf(float f) {
    __hip_bfloat16 h = __float2bfloat16(f);   // RNE
    union { __hip_bfloat16 h; unsigned short u; } v; v.h = h; return v.u;
}
DEVI unsigned pk2(float lo, float hi) {
    return (unsigned)f2bf(lo) | ((unsigned)f2bf(hi) << 16);
}
DEVI f32x4 zero4() { f32x4 z; z[0] = z[1] = z[2] = z[3] = 0.f; return z; }
DEVI f32x16 zero16() {
    f32x16 z;
#pragma unroll
    for (int i = 0; i < 16; ++i) z[i] = 0.f;
    return z;
}

// ---------------------------------------------------------------------------
// ws layout:
//   qbf [1024][64][256] bf16 @ 0           natural
//   kbf [2048][64][256] bf16 @ 33554432    natural
//   vbf [2048][64][256] bf16 @ 100663296   natural
//   partial [4][4096][128] f32 @ 167772160
//   pbf [4096][128] bf16 @ 176160768
// ---------------------------------------------------------------------------

// ============================ proj q ============================
// block = one image. Stage X bf16 in LDS [c][p] (stride 260). MFMA A=X-frag,
// B=W-frag => D[p][o]: lane holds 4 consecutive p at fixed o -> u32x2 stores.
__global__ __launch_bounds__(256) void proj_q_kernel(
    const float* __restrict__ qq, const float* __restrict__ Wq,
    const float* __restrict__ bq, unsigned short* __restrict__ qbf)
{
    __shared__ unsigned short Xs[64 * 260];
    const int tid = threadIdx.x;
    const int w = tid >> 6, lane = tid & 63;
    const int l15 = lane & 15, lg = lane >> 4;
    const int n = blockIdx.x;
    const float* xg = qq + (size_t)n * 16384;
    unsigned short* o1 = qbf + (size_t)n * 16384;

#pragma unroll
    for (int it = 0; it < 16; ++it) {
        const float* src = xg + it * 1024 + tid * 4;
        f32x4 xv = *(const f32x4*)src;
        u32x2 dd;
        dd[0] = pk2(xv[0], xv[1]);
        dd[1] = pk2(xv[2], xv[3]);
        *(u32x2*)(&Xs[(it * 4 + w) * 260 + lane * 4]) = dd;
    }

    bf16x8 bf1[4][2];
    float bias1[4];
#pragma unroll
    for (int ot = 0; ot < 4; ++ot) {
        const int o = ot * 16 + l15;
        bias1[ot] = bq[o];
#pragma unroll
        for (int ks = 0; ks < 2; ++ks) {
            const float* wp = Wq + o * 64 + ks * 32 + lg * 8;
            f32x4 w0 = *(const f32x4*)wp, w1 = *(const f32x4*)(wp + 4);
            bf16x8 a;
#pragma unroll
            for (int j = 0; j < 4; ++j) { a[j] = (short)f2bf(w0[j]); a[4 + j] = (short)f2bf(w1[j]); }
            bf1[ot][ks] = a;
        }
    }
    __syncthreads();

#pragma unroll
    for (int pt = 0; pt < 4; ++pt) {
        const int p0 = w * 64 + pt * 16;
        bf16x8 afr[2];
#pragma unroll
        for (int ks = 0; ks < 2; ++ks) {
            bf16x8 e;
#pragma unroll
            for (int j = 0; j < 8; ++j)
                e[j] = (short)Xs[(ks * 32 + lg * 8 + j) * 260 + p0 + l15];
            afr[ks] = e;
        }
        const int pb = p0 + lg * 4;
#pragma unroll
        for (int ot = 0; ot < 4; ++ot) {
            const int o = ot * 16 + l15;
            f32x4 a1 = zero4();
            a1 = __builtin_amdgcn_mfma_f32_16x16x32_bf16(afr[0], bf1[ot][0], a1, 0, 0, 0);
            a1 = __builtin_amdgcn_mfma_f32_16x16x32_bf16(afr[1], bf1[ot][1], a1, 0, 0, 0);
            u32x2 sv;
            sv[0] = pk2(a1[0] + bias1[ot], a1[1] + bias1[ot]);
            sv[1] = pk2(a1[2] + bias1[ot], a1[3] + bias1[ot]);
            *(u32x2*)(o1 + (size_t)o * 256 + pb) = sv;
        }
    }
}

// ============================ proj k + v ============================
// same structure; one X staging feeds both k and v; BOTH natural packed stores
__global__ __launch_bounds__(256) void proj_kv_kernel(
    const float* __restrict__ kvg,
    const float* __restrict__ Wk, const float* __restrict__ bk,
    const float* __restrict__ Wv, const float* __restrict__ bv,
    unsigned short* __restrict__ kbf, unsigned short* __restrict__ vbf)
{
    __shared__ unsigned short Xs[64 * 260];
    const int tid = threadIdx.x;
    const int w = tid >> 6, lane = tid & 63;
    const int l15 = lane & 15, lg = lane >> 4;
    const int n = blockIdx.x;
    const float* xg = kvg + (size_t)n * 16384;
    unsigned short* ok = kbf + (size_t)n * 16384;
    unsigned short* ov = vbf + (size_t)n * 16384;

#pragma unroll
    for (int it = 0; it < 16; ++it) {
        const float* src = xg + it * 1024 + tid * 4;
        f32x4 xv = *(const f32x4*)src;
        u32x2 dd;
        dd[0] = pk2(xv[0], xv[1]);
        dd[1] = pk2(xv[2], xv[3]);
        *(u32x2*)(&Xs[(it * 4 + w) * 260 + lane * 4]) = dd;
    }

    bf16x8 bf1[4][2], bf2[4][2];
    float bias1[4], bias2[4];
#pragma unroll
    for (int ot = 0; ot < 4; ++ot) {
        const int o = ot * 16 + l15;
        bias1[ot] = bk[o];
        bias2[ot] = bv[o];
#pragma unroll
        for (int ks = 0; ks < 2; ++ks) {
            const float* wkp = Wk + o * 64 + ks * 32 + lg * 8;
            const float* wvp = Wv + o * 64 + ks * 32 + lg * 8;
            f32x4 k0 = *(const f32x4*)wkp, k1 = *(const f32x4*)(wkp + 4);
            f32x4 v0 = *(const f32x4*)wvp, v1 = *(const f32x4*)(wvp + 4);
            bf16x8 a, c;
#pragma unroll
            for (int j = 0; j < 4; ++j) {
                a[j] = (short)f2bf(k0[j]); a[4 + j] = (short)f2bf(k1[j]);
                c[j] = (short)f2bf(v0[j]); c[4 + j] = (short)f2bf(v1[j]);
            }
            bf1[ot][ks] = a; bf2[ot][ks] = c;
        }
    }
    __syncthreads();

#pragma unroll
    for (int pt = 0; pt < 4; ++pt) {
        const int p0 = w * 64 + pt * 16;
        bf16x8 afr[2];
#pragma unroll
        for (int ks = 0; ks < 2; ++ks) {
            bf16x8 e;
#pragma unroll
            for (int j = 0; j < 8; ++j)
                e[j] = (short)Xs[(ks * 32 + lg * 8 + j) * 260 + p0 + l15];
            afr[ks] = e;
        }
        const int pb = p0 + lg * 4;
#pragma unroll
        for (int ot = 0; ot < 4; ++ot) {
            const int o = ot * 16 + l15;
            f32x4 a1 = zero4(), a2 = zero4();
            a1 = __builtin_amdgcn_mfma_f32_16x16x32_bf16(afr[0], bf1[ot][0], a1, 0, 0, 0);
            a1 = __builtin_amdgcn_mfma_f32_16x16x32_bf16(afr[1], bf1[ot][1], a1, 0, 0, 0);
            a2 = __builtin_amdgcn_mfma_f32_16x16x32_bf16(afr[0], bf2[ot][0], a2, 0, 0, 0);
            a2 = __builtin_amdgcn_mfma_f32_16x16x32_bf16(afr[1], bf2[ot][1], a2, 0, 0, 0);
            u32x2 sk, sv;
            sk[0] = pk2(a1[0] + bias1[ot], a1[1] + bias1[ot]);
            sk[1] = pk2(a1[2] + bias1[ot], a1[3] + bias1[ot]);
            sv[0] = pk2(a2[0] + bias2[ot], a2[1] + bias2[ot]);
            sv[1] = pk2(a2[2] + bias2[ot], a2[3] + bias2[ot]);
            *(u32x2*)(ok + (size_t)o * 256 + pb) = sk;
            *(u32x2*)(ov + (size_t)o * 256 + pb) = sv;
        }
    }
}

// ============================ sim (Q.K^T partials, K-split x4) ============================
__global__ __launch_bounds__(128) void sim_kernel(
    const unsigned short* __restrict__ qbf, const unsigned short* __restrict__ kbf,
    float* __restrict__ partial)
{
    const int tid = threadIdx.x;
    const int w = tid >> 6, lane = tid & 63;
    const int l31 = lane & 31, lh = lane >> 5;
    const int bh = blockIdx.x & 63, ks = blockIdx.x >> 6;
    const int b = bh >> 2, head = bh & 3;
    const int t0 = w * 64;

    const unsigned short* qbase = qbf + (size_t)b * 64 * 16384 + head * 4096;
    const unsigned short* kbase = kbf + (size_t)b * 128 * 16384 + head * 4096;

    f32x16 acc00 = zero16(), acc01 = zero16(), acc10 = zero16(), acc11 = zero16();
    const int kk0 = ks * 1024;
    for (int kk = 0; kk < 64; ++kk) {
        int k = kk0 + kk * 16 + lh * 8;
        bf16x8 a0 = *(const bf16x8*)(qbase + (size_t)(l31)      * 16384 + k);
        bf16x8 a1 = *(const bf16x8*)(qbase + (size_t)(l31 + 32) * 16384 + k);
        bf16x8 b0 = *(const bf16x8*)(kbase + (size_t)(t0 + l31)      * 16384 + k);
        bf16x8 b1 = *(const bf16x8*)(kbase + (size_t)(t0 + 32 + l31) * 16384 + k);
        acc00 = __builtin_amdgcn_mfma_f32_32x32x16_bf16(a0, b0, acc00, 0, 0, 0);
        acc01 = __builtin_amdgcn_mfma_f32_32x32x16_bf16(a0, b1, acc01, 0, 0, 0);
        acc10 = __builtin_amdgcn_mfma_f32_32x32x16_bf16(a1, b0, acc10, 0, 0, 0);
        acc11 = __builtin_amdgcn_mfma_f32_32x32x16_bf16(a1, b1, acc11, 0, 0, 0);
    }

    float* pb = partial + ((size_t)ks * 4096 + (size_t)bh * 64) * 128;
#pragma unroll
    for (int r = 0; r < 16; ++r) {
        int kqr = (r & 3) + 8 * (r >> 2) + 4 * lh;
        pb[(kqr)      * 128 + t0 + l31]      = acc00[r];
        pb[(kqr)      * 128 + t0 + 32 + l31] = acc01[r];
        pb[(kqr + 32) * 128 + t0 + l31]      = acc10[r];
        pb[(kqr + 32) * 128 + t0 + 32 + l31] = acc11[r];
    }
}

// ============================ softmax ============================
__global__ __launch_bounds__(256) void softmax_kernel(
    const float* __restrict__ partial, float* __restrict__ sim_out,
    unsigned short* __restrict__ pbf)
{
    const int tid = threadIdx.x;
    const int w = tid >> 6, lane = tid & 63;
    const int row = blockIdx.x * 4 + w;

    float x0 = 0.f, x1 = 0.f;
#pragma unroll
    for (int s = 0; s < 4; ++s) {
        x0 += partial[((size_t)s * 4096 + row) * 128 + lane];
        x1 += partial[((size_t)s * 4096 + row) * 128 + 64 + lane];
    }
    const float scale = 1.0f / 64.0f;
    x0 *= scale; x1 *= scale;
    float m = fmaxf(x0, x1);
#pragma unroll
    for (int off = 32; off; off >>= 1) m = fmaxf(m, __shfl_xor(m, off));
    float e0 = __expf(x0 - m), e1 = __expf(x1 - m);
    float s = e0 + e1;
#pragma unroll
    for (int off = 32; off; off >>= 1) s += __shfl_xor(s, off);
    float inv = 1.0f / s;
    float p0 = e0 * inv, p1 = e1 * inv;
    sim_out[(size_t)row * 128 + lane]      = p0;
    sim_out[(size_t)row * 128 + 64 + lane] = p1;
    pbf[(size_t)row * 128 + lane]      = f2bf(p0);
    pbf[(size_t)row * 128 + 64 + lane] = f2bf(p1);
}

// ============================ PV (natural V, coalesced transpose-on-read) ============================
__global__ __launch_bounds__(256) void pv_kernel(
    const unsigned short* __restrict__ pbf, const unsigned short* __restrict__ vbf,
    float* __restrict__ outp)
{
    const int tid = threadIdx.x;
    const int w = tid >> 6, lane = tid & 63;
    const int l31 = lane & 31, lh = lane >> 5;
    const int bh = blockIdx.x >> 4, cb = blockIdx.x & 15;
    const int b = bh >> 2, h = bh & 3;
    const int ch = h * 16 + cb;
    const int p0 = w * 64;

    const unsigned short* pb = pbf + (size_t)bh * 64 * 128;
    const unsigned short* vb = vbf + (size_t)b * 128 * 16384 + (size_t)ch * 256;

    f32x16 acc00 = zero16(), acc01 = zero16(), acc10 = zero16(), acc11 = zero16();
    for (int kk = 0; kk < 8; ++kk) {
        const int t0 = kk * 16;
        bf16x8 a0 = *(const bf16x8*)(pb + (size_t)l31 * 128 + t0 + lh * 8);
        bf16x8 a1 = *(const bf16x8*)(pb + (size_t)(l31 + 32) * 128 + t0 + lh * 8);
        bf16x8 b0, b1;
#pragma unroll
        for (int j = 0; j < 8; ++j) {
            const unsigned short* vr = vb + (size_t)(t0 + lh * 8 + j) * 16384;
            b0[j] = (short)vr[p0 + l31];
            b1[j] = (short)vr[p0 + 32 + l31];
        }
        acc00 = __builtin_amdgcn_mfma_f32_32x32x16_bf16(a0, b0, acc00, 0, 0, 0);
        acc01 = __builtin_amdgcn_mfma_f32_32x32x16_bf16(a0, b1, acc01, 0, 0, 0);
        acc10 = __builtin_amdgcn_mfma_f32_32x32x16_bf16(a1, b0, acc10, 0, 0, 0);
        acc11 = __builtin_amdgcn_mfma_f32_32x32x16_bf16(a1, b1, acc11, 0, 0, 0);
    }

    float* ob = outp + (size_t)b * 64 * 16384 + (size_t)ch * 256;
#pragma unroll
    for (int r = 0; r < 16; ++r) {
        int kqr = (r & 3) + 8 * (r >> 2) + 4 * lh;
        ob[(size_t)(kqr)      * 16384 + p0 + l31]      = acc00[r];
        ob[(size_t)(kqr)      * 16384 + p0 + 32 + l31] = acc01[r];
        ob[(size_t)(kqr + 32) * 16384 + p0 + l31]      = acc10[r];
        ob[(size_t)(kqr + 32) * 16384 + p0 + 32 + l31] = acc11[r];
    }
}

// ============================ launch ============================
extern "C" void kernel_launch(void* const* d_in, const int* in_sizes, int n_in,
                              void* d_out, int out_size, void* d_ws, size_t ws_size,
                              hipStream_t stream)
{
    const float* qq = (const float*)d_in[0];
    const float* kv = (const float*)d_in[1];
    const float* Wq = (const float*)d_in[2];
    const float* bq = (const float*)d_in[3];
    const float* Wk = (const float*)d_in[4];
    const float* bk = (const float*)d_in[5];
    const float* Wv = (const float*)d_in[6];
    const float* bv = (const float*)d_in[7];

    float* outp    = (float*)d_out;
    float* sim_out = outp + (size_t)16777216;

    char* ws = (char*)d_ws;
    unsigned short* qbf     = (unsigned short*)(ws);
    unsigned short* kbf     = (unsigned short*)(ws + 33554432);
    unsigned short* vbf     = (unsigned short*)(ws + 100663296);
    float*          partial = (float*)         (ws + 167772160);
    unsigned short* pbf     = (unsigned short*)(ws + 176160768);
    (void)in_sizes; (void)n_in; (void)out_size; (void)ws_size;

    proj_kv_kernel<<<dim3(2048), dim3(256), 0, stream>>>(kv, Wk, bk, Wv, bv, kbf, vbf);
    proj_q_kernel <<<dim3(1024), dim3(256), 0, stream>>>(qq, Wq, bq, qbf);
    sim_kernel    <<<dim3(256),  dim3(128), 0, stream>>>(qbf, kbf, partial);
    softmax_kernel<<<dim3(1024), dim3(256), 0, stream>>>(partial, sim_out, pbf);
    pv_kernel     <<<dim3(1024), dim3(256), 0, stream>>>(pbf, vbf, outp);
}

// Round 5
// 156.765 us; speedup vs baseline: 1.8049x; 1.2354x over previous
//
#include <hip/hip_runtime.h>
#include <hip/hip_bf16.h>
#include <stdint.h>
#include <stddef.h>

#define DEVI __device__ __forceinline__

typedef __attribute__((ext_vector_type(8)))  short bf16x8;
typedef __attribute__((ext_vector_type(4)))  float f32x4;
typedef __attribute__((ext_vector_type(16))) float f32x16;
typedef __attribute__((ext_vector_type(2)))  unsigned u32x2;

DEVI unsigned short f2bf(float f) {
    __hip_bfloat16 h = __float2bfloat16(f);   // RNE
    union { __hip_bfloat16 h; unsigned short u; } v; v.h = h; return v.u;
}
DEVI unsigned pk2(float lo, float hi) {
    return (unsigned)f2bf(lo) | ((unsigned)f2bf(hi) << 16);
}
DEVI f32x4 zero4() { f32x4 z; z[0] = z[1] = z[2] = z[3] = 0.f; return z; }
DEVI f32x16 zero16() {
    f32x16 z;
#pragma unroll
    for (int i = 0; i < 16; ++i) z[i] = 0.f;
    return z;
}

// ---------------------------------------------------------------------------
// ws layout:
//   qbf [1024][64][256] bf16 @ 0           natural
//   kbf [2048][64][256] bf16 @ 33554432    natural
//   vbf [2048][64][256] bf16 @ 100663296   natural
//   partial [4][4096][128] f32 @ 167772160
//   pbf [4096][128] bf16 @ 176160768
// ---------------------------------------------------------------------------
// proj structure (per image/block, 256 threads):
//   1. stage X fp32->bf16 into LDS [c][p] stride 260     (coalesced loads)
//   2. preload all 8 A-frags (X) into regs; LDS now dead
//   3. per output (k then v): MFMA tiles -> pack -> LDS [o][p] stride 264
//   4. copy-out: wave-contiguous dwordx4, 1KB/instr      (coalesced stores)
// ---------------------------------------------------------------------------

DEVI void load_wfrags(const float* __restrict__ W, const float* __restrict__ B,
                      int l15, int lg, bf16x8 (&bf)[4][2], float (&bias)[4]) {
#pragma unroll
    for (int ot = 0; ot < 4; ++ot) {
        const int o = ot * 16 + l15;
        bias[ot] = B[o];
#pragma unroll
        for (int ks = 0; ks < 2; ++ks) {
            const float* wp = W + o * 64 + ks * 32 + lg * 8;
            f32x4 w0 = *(const f32x4*)wp, w1 = *(const f32x4*)(wp + 4);
            bf16x8 a;
#pragma unroll
            for (int j = 0; j < 4; ++j) { a[j] = (short)f2bf(w0[j]); a[4 + j] = (short)f2bf(w1[j]); }
            bf[ot][ks] = a;
        }
    }
}

// compute one output (16 tiles), stage in LDS [o][264], coalesced copy-out
DEVI void proj_emit(unsigned short* __restrict__ S, const bf16x8 (&afr)[4][2],
                    const bf16x8 (&bf)[4][2], const float (&bias)[4],
                    int tid, int w, int l15, int lg,
                    unsigned short* __restrict__ og) {
#pragma unroll
    for (int pt = 0; pt < 4; ++pt) {
        const int p = w * 64 + pt * 16 + lg * 4;
#pragma unroll
        for (int ot = 0; ot < 4; ++ot) {
            const int o = ot * 16 + l15;
            f32x4 a1 = zero4();
            a1 = __builtin_amdgcn_mfma_f32_16x16x32_bf16(afr[pt][0], bf[ot][0], a1, 0, 0, 0);
            a1 = __builtin_amdgcn_mfma_f32_16x16x32_bf16(afr[pt][1], bf[ot][1], a1, 0, 0, 0);
            u32x2 sv;
            sv[0] = pk2(a1[0] + bias[ot], a1[1] + bias[ot]);
            sv[1] = pk2(a1[2] + bias[ot], a1[3] + bias[ot]);
            *(u32x2*)(&S[o * 264 + p]) = sv;
        }
    }
    __syncthreads();
    // copy out: 8 iters x (64 lanes x 16B) = full [64][256] bf16, contiguous
#pragma unroll
    for (int it = 0; it < 8; ++it) {
        const int idx = it * 256 + tid;           // 0..2047
        const int o = idx >> 5, px = (idx & 31) * 8;
        f32x4 vv = *(const f32x4*)(&S[o * 264 + px]);
        *(f32x4*)(og + (size_t)o * 256 + px) = vv;
    }
}

// ============================ proj q ============================
__global__ __launch_bounds__(256) void proj_q_kernel(
    const float* __restrict__ qq, const float* __restrict__ Wq,
    const float* __restrict__ bq, unsigned short* __restrict__ qbf)
{
    __shared__ unsigned short S[64 * 264];
    const int tid = threadIdx.x;
    const int w = tid >> 6, lane = tid & 63;
    const int l15 = lane & 15, lg = lane >> 4;
    const int n = blockIdx.x;
    const float* xg = qq + (size_t)n * 16384;

    // stage X -> LDS bf16 [c][260]
#pragma unroll
    for (int it = 0; it < 16; ++it) {
        const float* src = xg + it * 1024 + tid * 4;
        f32x4 xv = *(const f32x4*)src;
        u32x2 dd; dd[0] = pk2(xv[0], xv[1]); dd[1] = pk2(xv[2], xv[3]);
        *(u32x2*)(&S[(it * 4 + w) * 260 + lane * 4]) = dd;
    }
    bf16x8 bf1[4][2]; float bias1[4];
    load_wfrags(Wq, bq, l15, lg, bf1, bias1);
    __syncthreads();

    // preload all A-frags; LDS becomes dead after the next sync
    bf16x8 afr[4][2];
#pragma unroll
    for (int pt = 0; pt < 4; ++pt) {
        const int p0 = w * 64 + pt * 16;
#pragma unroll
        for (int ks = 0; ks < 2; ++ks) {
            bf16x8 e;
#pragma unroll
            for (int j = 0; j < 8; ++j)
                e[j] = (short)S[(ks * 32 + lg * 8 + j) * 260 + p0 + l15];
            afr[pt][ks] = e;
        }
    }
    __syncthreads();

    proj_emit(S, afr, bf1, bias1, tid, w, l15, lg, qbf + (size_t)n * 16384);
}

// ============================ proj k + v ============================
__global__ __launch_bounds__(256) void proj_kv_kernel(
    const float* __restrict__ kvg,
    const float* __restrict__ Wk, const float* __restrict__ bk,
    const float* __restrict__ Wv, const float* __restrict__ bv,
    unsigned short* __restrict__ kbf, unsigned short* __restrict__ vbf)
{
    __shared__ unsigned short S[64 * 264];
    const int tid = threadIdx.x;
    const int w = tid >> 6, lane = tid & 63;
    const int l15 = lane & 15, lg = lane >> 4;
    const int n = blockIdx.x;
    const float* xg = kvg + (size_t)n * 16384;

#pragma unroll
    for (int it = 0; it < 16; ++it) {
        const float* src = xg + it * 1024 + tid * 4;
        f32x4 xv = *(const f32x4*)src;
        u32x2 dd; dd[0] = pk2(xv[0], xv[1]); dd[1] = pk2(xv[2], xv[3]);
        *(u32x2*)(&S[(it * 4 + w) * 260 + lane * 4]) = dd;
    }
    bf16x8 bf1[4][2]; float bias1[4];
    load_wfrags(Wk, bk, l15, lg, bf1, bias1);
    __syncthreads();

    bf16x8 afr[4][2];
#pragma unroll
    for (int pt = 0; pt < 4; ++pt) {
        const int p0 = w * 64 + pt * 16;
#pragma unroll
        for (int ks = 0; ks < 2; ++ks) {
            bf16x8 e;
#pragma unroll
            for (int j = 0; j < 8; ++j)
                e[j] = (short)S[(ks * 32 + lg * 8 + j) * 260 + p0 + l15];
            afr[pt][ks] = e;
        }
    }
    __syncthreads();

    // k pass
    proj_emit(S, afr, bf1, bias1, tid, w, l15, lg, kbf + (size_t)n * 16384);
    __syncthreads();
    // v pass (reuse the same frag registers; reload W frags as Wv)
    load_wfrags(Wv, bv, l15, lg, bf1, bias1);
    proj_emit(S, afr, bf1, bias1, tid, w, l15, lg, vbf + (size_t)n * 16384);
}

// ============================ sim (Q.K^T partials, K-split x4) ============================
__global__ __launch_bounds__(128) void sim_kernel(
    const unsigned short* __restrict__ qbf, const unsigned short* __restrict__ kbf,
    float* __restrict__ partial)
{
    const int tid = threadIdx.x;
    const int w = tid >> 6, lane = tid & 63;
    const int l31 = lane & 31, lh = lane >> 5;
    const int bh = blockIdx.x & 63, ks = blockIdx.x >> 6;
    const int b = bh >> 2, head = bh & 3;
    const int t0 = w * 64;

    const unsigned short* qbase = qbf + (size_t)b * 64 * 16384 + head * 4096;
    const unsigned short* kbase = kbf + (size_t)b * 128 * 16384 + head * 4096;

    f32x16 acc00 = zero16(), acc01 = zero16(), acc10 = zero16(), acc11 = zero16();
    const int kk0 = ks * 1024;
    for (int kk = 0; kk < 64; ++kk) {
        int k = kk0 + kk * 16 + lh * 8;
        bf16x8 a0 = *(const bf16x8*)(qbase + (size_t)(l31)      * 16384 + k);
        bf16x8 a1 = *(const bf16x8*)(qbase + (size_t)(l31 + 32) * 16384 + k);
        bf16x8 b0 = *(const bf16x8*)(kbase + (size_t)(t0 + l31)      * 16384 + k);
        bf16x8 b1 = *(const bf16x8*)(kbase + (size_t)(t0 + 32 + l31) * 16384 + k);
        acc00 = __builtin_amdgcn_mfma_f32_32x32x16_bf16(a0, b0, acc00, 0, 0, 0);
        acc01 = __builtin_amdgcn_mfma_f32_32x32x16_bf16(a0, b1, acc01, 0, 0, 0);
        acc10 = __builtin_amdgcn_mfma_f32_32x32x16_bf16(a1, b0, acc10, 0, 0, 0);
        acc11 = __builtin_amdgcn_mfma_f32_32x32x16_bf16(a1, b1, acc11, 0, 0, 0);
    }

    float* pb = partial + ((size_t)ks * 4096 + (size_t)bh * 64) * 128;
#pragma unroll
    for (int r = 0; r < 16; ++r) {
        int kqr = (r & 3) + 8 * (r >> 2) + 4 * lh;
        pb[(kqr)      * 128 + t0 + l31]      = acc00[r];
        pb[(kqr)      * 128 + t0 + 32 + l31] = acc01[r];
        pb[(kqr + 32) * 128 + t0 + l31]      = acc10[r];
        pb[(kqr + 32) * 128 + t0 + 32 + l31] = acc11[r];
    }
}

// ============================ softmax ============================
__global__ __launch_bounds__(256) void softmax_kernel(
    const float* __restrict__ partial, float* __restrict__ sim_out,
    unsigned short* __restrict__ pbf)
{
    const int tid = threadIdx.x;
    const int w = tid >> 6, lane = tid & 63;
    const int row = blockIdx.x * 4 + w;

    float x0 = 0.f, x1 = 0.f;
#pragma unroll
    for (int s = 0; s < 4; ++s) {
        x0 += partial[((size_t)s * 4096 + row) * 128 + lane];
        x1 += partial[((size_t)s * 4096 + row) * 128 + 64 + lane];
    }
    const float scale = 1.0f / 64.0f;
    x0 *= scale; x1 *= scale;
    float m = fmaxf(x0, x1);
#pragma unroll
    for (int off = 32; off; off >>= 1) m = fmaxf(m, __shfl_xor(m, off));
    float e0 = __expf(x0 - m), e1 = __expf(x1 - m);
    float s = e0 + e1;
#pragma unroll
    for (int off = 32; off; off >>= 1) s += __shfl_xor(s, off);
    float inv = 1.0f / s;
    float p0 = e0 * inv, p1 = e1 * inv;
    sim_out[(size_t)row * 128 + lane]      = p0;
    sim_out[(size_t)row * 128 + 64 + lane] = p1;
    pbf[(size_t)row * 128 + lane]      = f2bf(p0);
    pbf[(size_t)row * 128 + 64 + lane] = f2bf(p1);
}

// ============================ PV (natural V, coalesced transpose-on-read) ============================
__global__ __launch_bounds__(256) void pv_kernel(
    const unsigned short* __restrict__ pbf, const unsigned short* __restrict__ vbf,
    float* __restrict__ outp)
{
    const int tid = threadIdx.x;
    const int w = tid >> 6, lane = tid & 63;
    const int l31 = lane & 31, lh = lane >> 5;
    const int bh = blockIdx.x >> 4, cb = blockIdx.x & 15;
    const int b = bh >> 2, h = bh & 3;
    const int ch = h * 16 + cb;
    const int p0 = w * 64;

    const unsigned short* pb = pbf + (size_t)bh * 64 * 128;
    const unsigned short* vb = vbf + (size_t)b * 128 * 16384 + (size_t)ch * 256;

    f32x16 acc00 = zero16(), acc01 = zero16(), acc10 = zero16(), acc11 = zero16();
    for (int kk = 0; kk < 8; ++kk) {
        const int t0 = kk * 16;
        bf16x8 a0 = *(const bf16x8*)(pb + (size_t)l31 * 128 + t0 + lh * 8);
        bf16x8 a1 = *(const bf16x8*)(pb + (size_t)(l31 + 32) * 128 + t0 + lh * 8);
        bf16x8 b0, b1;
#pragma unroll
        for (int j = 0; j < 8; ++j) {
            const unsigned short* vr = vb + (size_t)(t0 + lh * 8 + j) * 16384;
            b0[j] = (short)vr[p0 + l31];
            b1[j] = (short)vr[p0 + 32 + l31];
        }
        acc00 = __builtin_amdgcn_mfma_f32_32x32x16_bf16(a0, b0, acc00, 0, 0, 0);
        acc01 = __builtin_amdgcn_mfma_f32_32x32x16_bf16(a0, b1, acc01, 0, 0, 0);
        acc10 = __builtin_amdgcn_mfma_f32_32x32x16_bf16(a1, b0, acc10, 0, 0, 0);
        acc11 = __builtin_amdgcn_mfma_f32_32x32x16_bf16(a1, b1, acc11, 0, 0, 0);
    }

    float* ob = outp + (size_t)b * 64 * 16384 + (size_t)ch * 256;
#pragma unroll
    for (int r = 0; r < 16; ++r) {
        int kqr = (r & 3) + 8 * (r >> 2) + 4 * lh;
        ob[(size_t)(kqr)      * 16384 + p0 + l31]      = acc00[r];
        ob[(size_t)(kqr)      * 16384 + p0 + 32 + l31] = acc01[r];
        ob[(size_t)(kqr + 32) * 16384 + p0 + l31]      = acc10[r];
        ob[(size_t)(kqr + 32) * 16384 + p0 + 32 + l31] = acc11[r];
    }
}

// ============================ launch ============================
extern "C" void kernel_launch(void* const* d_in, const int* in_sizes, int n_in,
                              void* d_out, int out_size, void* d_ws, size_t ws_size,
                              hipStream_t stream)
{
    const float* qq = (const float*)d_in[0];
    const float* kv = (const float*)d_in[1];
    const float* Wq = (const float*)d_in[2];
    const float* bq = (const float*)d_in[3];
    const float* Wk = (const float*)d_in[4];
    const float* bk = (const float*)d_in[5];
    const float* Wv = (const float*)d_in[6];
    const float* bv = (const float*)d_in[7];

    float* outp    = (float*)d_out;
    float* sim_out = outp + (size_t)16777216;

    char* ws = (char*)d_ws;
    unsigned short* qbf     = (unsigned short*)(ws);
    unsigned short* kbf     = (unsigned short*)(ws + 33554432);
    unsigned short* vbf     = (unsigned short*)(ws + 100663296);
    float*          partial = (float*)         (ws + 167772160);
    unsigned short* pbf     = (unsigned short*)(ws + 176160768);
    (void)in_sizes; (void)n_in; (void)out_size; (void)ws_size;

    proj_kv_kernel<<<dim3(2048), dim3(256), 0, stream>>>(kv, Wk, bk, Wv, bv, kbf, vbf);
    proj_q_kernel <<<dim3(1024), dim3(256), 0, stream>>>(qq, Wq, bq, qbf);
    sim_kernel    <<<dim3(256),  dim3(128), 0, stream>>>(qbf, kbf, partial);
    softmax_kernel<<<dim3(1024), dim3(256), 0, stream>>>(partial, sim_out, pbf);
    pv_kernel     <<<dim3(1024), dim3(256), 0, stream>>>(pbf, vbf, outp);
}